// Round 5
// baseline (338.102 us; speedup 1.0000x reference)
//
#include <hip/hip_runtime.h>
#include <cstddef>

// Problem constants: B=32, N=4096, D=256, K=8 slots, S=16, H=128, 3 iters.

__device__ __forceinline__ float sigmoid_f(float x){ return 1.f/(1.f+__expf(-x)); }
__device__ __forceinline__ float tanh_f(float x){ return 1.f - 2.f/(__expf(2.f*x)+1.f); }

// async global->LDS, 16 B per lane; lds dest = wave-uniform base + lane*16.
__device__ __forceinline__ void load16_to_lds(const float* g, float* l) {
  __builtin_amdgcn_global_load_lds(
      (const __attribute__((address_space(1))) unsigned int*)g,
      (__attribute__((address_space(3))) unsigned int*)l,
      16, 0, 0);
}

// ---------------- K0: prep (weights, init slots, q1, zero accumulators) ----
// Grid = 32 blocks. wprepT layout: [c][p][u][d64] (c = 64-col chunk, p = wave,
// u = output-within-wave; actual output s = p*8+u, col d = c*64+d64), LN-scaled:
// element = lnw[d] * w[s][d]. Each (c,p) slab is 512 contiguous floats.
__global__ __launch_bounds__(256) void k_prep(
    const float* __restrict__ lnw, const float* __restrict__ lnb,
    const float* __restrict__ wk, const float* __restrict__ wv,
    const float* __restrict__ init_slots,
    const float* __restrict__ ln_s_w, const float* __restrict__ ln_s_b,
    const float* __restrict__ wq,
    float* __restrict__ wprepT, float* __restrict__ mt,
    float* __restrict__ qbuf, float* __restrict__ upd, float* __restrict__ Abuf,
    float* __restrict__ slots_out)
{
  int t = threadIdx.x;
  int i = blockIdx.x*256 + t;          // 32*256 == 8192 exactly
  {
    int d64 = i & 63, u = (i >> 6) & 7, p = (i >> 9) & 3, c = i >> 11;
    int s = p*8 + u, d = c*64 + d64;
    float w = (s < 16) ? wk[s*256+d] : wv[(s-16)*256+d];
    wprepT[i] = lnw[d]*w;
  }
  if (blockIdx.x != 0) return;
  // m[s] = sum_d lnw*w ; t[s] = sum_d lnb*w   (32 s-values x 8 lanes each)
  {
    int s = t >> 3, j = t & 7;
    float m = 0.f, tv = 0.f;
    for (int d = j; d < 256; d += 8) {
      float w = (s < 16) ? wk[s*256+d] : wv[(s-16)*256+d];
      m  = fmaf(lnw[d], w, m);
      tv = fmaf(lnb[d], w, tv);
    }
    m += __shfl_xor(m,1);  m += __shfl_xor(m,2);  m += __shfl_xor(m,4);
    tv += __shfl_xor(tv,1); tv += __shfl_xor(tv,2); tv += __shfl_xor(tv,4);
    if (j == 0) { mt[s] = m; mt[32+s] = tv; }
  }
  // init slots into d_out, zero accumulators (ws is poisoned before each launch)
  #pragma unroll
  for (int j2 = 0; j2 < 16; ++j2) {
    slots_out[t*16+j2] = init_slots[t*16+j2];
    upd[t*16+j2] = 0.f;
  }
  Abuf[t] = 0.f;
  // q for iteration 1: thread t = (b,k) row
  float sl[16];
  #pragma unroll
  for (int j2 = 0; j2 < 16; ++j2) sl[j2] = init_slots[t*16+j2];
  float mu = 0.f;
  #pragma unroll
  for (int j2 = 0; j2 < 16; ++j2) mu += sl[j2];
  mu *= (1.f/16.f);
  float var = 0.f;
  #pragma unroll
  for (int j2 = 0; j2 < 16; ++j2) { float d = sl[j2]-mu; var = fmaf(d,d,var); }
  var *= (1.f/16.f);
  float rstd = rsqrtf(var + 1e-5f);
  float y[16];
  #pragma unroll
  for (int j2 = 0; j2 < 16; ++j2) y[j2] = (sl[j2]-mu)*rstd*ln_s_w[j2] + ln_s_b[j2];
  #pragma unroll
  for (int tq = 0; tq < 16; ++tq) {
    float q = 0.f;
    #pragma unroll
    for (int s2 = 0; s2 < 16; ++s2) q = fmaf(y[s2], wq[tq*16+s2], q);
    qbuf[t*16+tq] = q;
  }
}

// ---------------- K1: fused LayerNorm + K/V projection ----------------
// Block = 256 threads = 4 waves, 64 rows. Double-buffered LINEAR 64x64 LDS
// tile staged via async global_load_lds (NO staging VGPRs -> no spill; the
// round-3/4 killer was spill-to-scratch washing 108 MB to HBM). Padding is
// forbidden by global_load_lds (dest = uniform base + lane*16), so bank
// conflicts are broken by a ROTATION swizzle applied on the global address
// side: data (row, colblock cb) lives at LDS word row*64 + ((cb+row)&15)*4;
// compute lane=row reads slot (m+row)&15 to get cb=m -> each 4-bank group
// serves 8 words = b128 structural floor (conflict-free). Weight index m is
// wave-uniform -> weights stay scalar s_loads. One barrier per chunk;
// prefetch of chunk c+1 issued before compute of chunk c.
__global__ __launch_bounds__(256, 4) void k_proj(
    const float* __restrict__ x, const float* __restrict__ wprepT,
    const float* __restrict__ mt,
    float* __restrict__ kout, float* __restrict__ vout)
{
  __shared__ float xs[2][64*64];      // 32 KiB
  int t = threadIdx.x;
  int lane = t & 63;
  int p = __builtin_amdgcn_readfirstlane(t >> 6);
  int r0 = blockIdx.x*64;
  const float* xbase = x + (size_t)r0*256;

  // staging geometry: wave p stages rows [p*16, p*16+16), 4 rows per instr;
  // lane covers (row = p*16 + i*4 + (lane>>4), slot = lane&15), fetching
  // global colblock cb = (slot - row) & 15 of chunk c.
  int sr = lane >> 4;                  // 0..3
  int slot = lane & 15;
  int row_st0 = p*16 + sr;             // i=0 row; +4 per i
  int cb0 = (slot - row_st0) & 15;     // rotation (row+4 keeps (…)&15 shifting)

  float acc[8];
  #pragma unroll
  for (int u = 0; u < 8; ++u) acc[u] = 0.f;
  float sum = 0.f, sumsq = 0.f;

  // issue chunk c into buffer buf
  #define ISSUE_CHUNK(c_, buf_)                                              \
    _Pragma("unroll")                                                        \
    for (int i = 0; i < 4; ++i) {                                            \
      int row = row_st0 + i*4;                                               \
      int cb  = (cb0 - i*4) & 15;                                            \
      load16_to_lds(xbase + (size_t)row*256 + (c_)*64 + cb*4,                \
                    &xs[buf_][(p*16 + i*4)*64]);                             \
    }

  ISSUE_CHUNK(0, 0)
  __syncthreads();                     // drains vmcnt -> chunk 0 in LDS

  #pragma unroll 1
  for (int c = 0; c < 4; ++c) {
    if (c < 3) { ISSUE_CHUNK(c+1, (c+1)&1) }   // lands by next barrier
    const float* wc = wprepT + (c*4 + p)*512;  // uniform -> s_load
    const float* xb = xs[c&1];
    #pragma unroll
    for (int g = 0; g < 4; ++g) {
      float xe[16];
      #pragma unroll
      for (int i = 0; i < 4; ++i) {
        int m = g*4 + i;
        float4 f = *(const float4*)&xb[lane*64 + ((m + lane) & 15)*4];
        xe[i*4+0]=f.x; xe[i*4+1]=f.y; xe[i*4+2]=f.z; xe[i*4+3]=f.w;
      }
      #pragma unroll
      for (int j = 0; j < 16; ++j) { sum += xe[j]; sumsq = fmaf(xe[j], xe[j], sumsq); }
      #pragma unroll
      for (int u = 0; u < 8; ++u) {
        const float* w = wc + u*64 + g*16;
        #pragma unroll
        for (int j = 0; j < 16; ++j) acc[u] = fmaf(xe[j], w[j], acc[u]);
      }
    }
    __syncthreads();   // seals reads of xs[c&1]; chunk c+1 fully landed
  }
  #undef ISSUE_CHUNK

  float mu = sum*(1.f/256.f);
  float var = sumsq*(1.f/256.f) - mu*mu;
  float rstd = rsqrtf(var + 1e-5f);
  float o[8];
  #pragma unroll
  for (int u = 0; u < 8; ++u) {
    int a = p*8 + u;                 // uniform
    o[u] = fmaf(rstd, acc[u] - mu*mt[a], mt[32+a]);
  }
  float* dst = ((p < 2) ? kout : vout) + (size_t)(r0 + lane)*16 + (p & 1)*8;
  *(float4*)(dst+0) = make_float4(o[0],o[1],o[2],o[3]);
  *(float4*)(dst+4) = make_float4(o[4],o[5],o[6],o[7]);
}

// ---------------- K2: logits + softmax-over-slots + update accumulation ----
// Block = (b, chunk of 256 n). Stage k tile [n][s] (stride 20) and v tile
// transposed [s][n] (stride 260) via coalesced loads. Phase 1: per-n softmax
// over 8 slots -> ptile (stride 260) + EPS, optional global attn write.
// Phase 2: threads = (kk,s,half), float4 over n, atomicAdd partials.
__global__ __launch_bounds__(256) void k_attn(
    const float* __restrict__ kproj, const float* __restrict__ vproj,
    const float* __restrict__ qbuf,
    float* __restrict__ upd, float* __restrict__ Abuf,
    float* __restrict__ attn_out, int write_attn)
{
  __shared__ float qs[128];
  __shared__ float ktile[256*20];
  __shared__ float vtile[16*260];
  __shared__ float ptile[8*260];
  int b = blockIdx.x >> 4;
  int n0 = (blockIdx.x & 15) * 256;
  int t = threadIdx.x;

  const float* kbase = kproj + ((size_t)(b*4096 + n0))*16;
  const float* vbase = vproj + ((size_t)(b*4096 + n0))*16;
  {
    int nn = t >> 2, s0 = (t & 3)*4;
    #pragma unroll
    for (int i = 0; i < 4; ++i) {
      int n = i*64 + nn;
      float4 kf = *(const float4*)(kbase + n*16 + s0);
      *(float4*)&ktile[n*20 + s0] = kf;
      float4 vf = *(const float4*)(vbase + n*16 + s0);
      vtile[(s0+0)*260 + n] = vf.x;
      vtile[(s0+1)*260 + n] = vf.y;
      vtile[(s0+2)*260 + n] = vf.z;
      vtile[(s0+3)*260 + n] = vf.w;
    }
  }
  if (t < 128) qs[t] = qbuf[b*128 + t];
  __syncthreads();

  {
    float4 kv[4];
    #pragma unroll
    for (int i = 0; i < 4; ++i) kv[i] = *(const float4*)&ktile[t*20 + i*4];
    const float4* q4 = (const float4*)qs;
    float lg[8];
    #pragma unroll
    for (int kk = 0; kk < 8; ++kk) {
      float4 a4 = make_float4(0.f,0.f,0.f,0.f);
      #pragma unroll
      for (int i = 0; i < 4; ++i) {
        float4 q = q4[kk*4+i];
        a4.x = fmaf(q.x, kv[i].x, a4.x);
        a4.y = fmaf(q.y, kv[i].y, a4.y);
        a4.z = fmaf(q.z, kv[i].z, a4.z);
        a4.w = fmaf(q.w, kv[i].w, a4.w);
      }
      lg[kk] = ((a4.x+a4.y)+(a4.z+a4.w))*0.25f;  // scale = 16^-0.5
    }
    float mx = lg[0];
    #pragma unroll
    for (int kk = 1; kk < 8; ++kk) mx = fmaxf(mx, lg[kk]);
    float se = 0.f;
    #pragma unroll
    for (int kk = 0; kk < 8; ++kk) { lg[kk] = __expf(lg[kk]-mx); se += lg[kk]; }
    float inv = 1.f/se;
    #pragma unroll
    for (int kk = 0; kk < 8; ++kk) {
      float pv = fmaf(lg[kk], inv, 1e-8f);   // softmax + EPS (pre-renorm)
      ptile[kk*260 + t] = pv;
      if (write_attn) attn_out[((size_t)(b*8+kk))*4096 + n0 + t] = pv;
    }
  }
  __syncthreads();
  {
    int kk = t >> 5, r = t & 31, s = r >> 1, half = r & 1;
    const float4* pr = (const float4*)(ptile + kk*260 + half*128);
    const float4* vr = (const float4*)(vtile + s*260 + half*128);
    float4 a4 = make_float4(0.f,0.f,0.f,0.f);
    float4 s4 = make_float4(0.f,0.f,0.f,0.f);
    #pragma unroll 8
    for (int i = 0; i < 32; ++i) {
      float4 pv = pr[i], vv = vr[i];
      s4.x += pv.x; s4.y += pv.y; s4.z += pv.z; s4.w += pv.w;
      a4.x = fmaf(pv.x, vv.x, a4.x);
      a4.y = fmaf(pv.y, vv.y, a4.y);
      a4.z = fmaf(pv.z, vv.z, a4.z);
      a4.w = fmaf(pv.w, vv.w, a4.w);
    }
    float acc  = (a4.x+a4.y)+(a4.z+a4.w);
    float asum = (s4.x+s4.y)+(s4.z+s4.w);
    acc  += __shfl_xor(acc, 1);
    asum += __shfl_xor(asum, 1);
    if (half == 0) {
      atomicAdd(upd + (b*8+kk)*16 + s, acc);
      if (s == 0) atomicAdd(Abuf + b*8 + kk, asum);
    }
  }
}

// ---------------- K3: GRU cell + LN + MLP + slots update + next-iter q -----
// 16 blocks x 256 threads; thread = (b,k,s); 16-lane group per (b,k).
__global__ __launch_bounds__(256) void k_gru(
    float* __restrict__ upd, float* __restrict__ Abuf,
    float* __restrict__ slots, float* __restrict__ qbuf,
    const float* __restrict__ w_ih, const float* __restrict__ w_hh,
    const float* __restrict__ b_ih, const float* __restrict__ b_hh,
    const float* __restrict__ mlp_w1, const float* __restrict__ mlp_b1,
    const float* __restrict__ mlp_w2, const float* __restrict__ mlp_b2,
    const float* __restrict__ ln_m_w, const float* __restrict__ ln_m_b,
    const float* __restrict__ ln_s_w, const float* __restrict__ ln_s_b,
    const float* __restrict__ wq, int prep_next)
{
  __shared__ float s_wih[48*17], s_whh[48*17];   // stride 17: conflict-free
  __shared__ float s_bih[48], s_bhh[48];
  __shared__ float s_w1[128*17], s_b1[128];
  __shared__ float s_w2[16*129], s_b2[16];       // stride 129: conflict-free
  __shared__ float s_lnmw[16], s_lnmb[16], s_lnsw[16], s_lnsb[16];
  __shared__ float s_wq[16*17];
  int t = threadIdx.x;
  for (int i = t; i < 768; i += 256) {
    int g = i >> 4, j = i & 15;
    s_wih[g*17+j] = w_ih[i];
    s_whh[g*17+j] = w_hh[i];
  }
  for (int i = t; i < 2048; i += 256) {
    int r = i >> 4, c = i & 15;
    s_w1[r*17+c] = mlp_w1[i];
    int r2 = i >> 7, c2 = i & 127;
    s_w2[r2*129+c2] = mlp_w2[i];
  }
  if (t < 48) { s_bih[t] = b_ih[t]; s_bhh[t] = b_hh[t]; }
  if (t < 128) s_b1[t] = mlp_b1[t];
  if (t < 16) {
    s_b2[t] = mlp_b2[t];
    s_lnmw[t] = ln_m_w[t]; s_lnmb[t] = ln_m_b[t];
    s_lnsw[t] = ln_s_w[t]; s_lnsb[t] = ln_s_b[t];
  }
  for (int i = t; i < 256; i += 256) {
    int r = i >> 4, c = i & 15;
    s_wq[r*17+c] = wq[i];
  }
  __syncthreads();

  int bk = blockIdx.x*16 + (t >> 4);
  int s = t & 15;
  int laneBase = (t & 63) & ~15;   // 16-lane group lives inside one wave

  float inv = 1.f / Abuf[bk];
  float u[16], h[16];
  #pragma unroll
  for (int j = 0; j < 16; ++j) {
    u[j] = upd[bk*16+j] * inv;     // normalized updates
    h[j] = slots[bk*16+j];         // slots_prev
  }
  float hs = slots[bk*16+s];       // avoid dynamic reg-array index

  float gir = s_bih[s],  giz = s_bih[16+s], gin = s_bih[32+s];
  float ghr = s_bhh[s],  ghz = s_bhh[16+s], ghn = s_bhh[32+s];
  #pragma unroll
  for (int j = 0; j < 16; ++j) {
    gir = fmaf(u[j], s_wih[s*17+j], gir);
    giz = fmaf(u[j], s_wih[(16+s)*17+j], giz);
    gin = fmaf(u[j], s_wih[(32+s)*17+j], gin);
    ghr = fmaf(h[j], s_whh[s*17+j], ghr);
    ghz = fmaf(h[j], s_whh[(16+s)*17+j], ghz);
    ghn = fmaf(h[j], s_whh[(32+s)*17+j], ghn);
  }
  float rr = sigmoid_f(gir + ghr);
  float zz = sigmoid_f(giz + ghz);
  float nn = tanh_f(gin + rr*ghn);
  float hn = (1.f-zz)*nn + zz*hs;

  // LayerNorm(h) over the 16-lane group
  float ssum = hn;
  #pragma unroll
  for (int m = 1; m < 16; m <<= 1) ssum += __shfl_xor(ssum, m);
  float mu = ssum*(1.f/16.f);
  float dv = hn - mu;
  float vs = dv*dv;
  #pragma unroll
  for (int m = 1; m < 16; m <<= 1) vs += __shfl_xor(vs, m);
  float rstd = rsqrtf(vs*(1.f/16.f) + 1e-5f);
  float y = dv*rstd*s_lnmw[s] + s_lnmb[s];

  float yv[16];
  #pragma unroll
  for (int j = 0; j < 16; ++j) yv[j] = __shfl(y, laneBase + j);

  // MLP layer 1: thread s owns hidden units j = i*16+s (bank-friendly)
  float h1[8];
  #pragma unroll
  for (int i = 0; i < 8; ++i) {
    int jj = i*16 + s;
    float a = s_b1[jj];
    #pragma unroll
    for (int q = 0; q < 16; ++q) a = fmaf(yv[q], s_w1[jj*17+q], a);
    h1[i] = fmaxf(a, 0.f);
  }
  // MLP layer 2 via shuffles
  float o = s_b2[s];
  #pragma unroll
  for (int i = 0; i < 8; ++i) {
    #pragma unroll
    for (int sp = 0; sp < 16; ++sp) {
      float hv = __shfl(h1[i], laneBase + sp);
      o = fmaf(hv, s_w2[s*129 + i*16 + sp], o);
    }
  }
  float slot_new = hn + o;
  slots[bk*16+s] = slot_new;

  if (prep_next) {
    // q for next iteration: wq @ LN_s(slots_new)
    float ss = slot_new;
    #pragma unroll
    for (int m = 1; m < 16; m <<= 1) ss += __shfl_xor(ss, m);
    float mu2 = ss*(1.f/16.f);
    float d2 = slot_new - mu2;
    float v2 = d2*d2;
    #pragma unroll
    for (int m = 1; m < 16; m <<= 1) v2 += __shfl_xor(v2, m);
    float rstd2 = rsqrtf(v2*(1.f/16.f) + 1e-5f);
    float y2 = d2*rstd2*s_lnsw[s] + s_lnsb[s];
    float qv = 0.f;
    #pragma unroll
    for (int sp = 0; sp < 16; ++sp) qv = fmaf(__shfl(y2, laneBase+sp), s_wq[s*17+sp], qv);
    qbuf[bk*16+s] = qv;
    // zero accumulators for next iteration (reads above are same-wave lockstep)
    upd[bk*16+s] = 0.f;
    if (s == 0) Abuf[bk] = 0.f;
  }
}

// ---------------- K4: normalize attn rows by A[b,k] ----------------
__global__ __launch_bounds__(256) void k_scale(float* __restrict__ attn,
                                               const float* __restrict__ Abuf)
{
  int bk = blockIdx.x;
  float inv = 1.f / Abuf[bk];
  float4* p = (float4*)(attn + (size_t)bk*4096);
  #pragma unroll 4
  for (int i = threadIdx.x; i < 1024; i += 256) {
    float4 v = p[i];
    v.x *= inv; v.y *= inv; v.z *= inv; v.w *= inv;
    p[i] = v;
  }
}

extern "C" void kernel_launch(void* const* d_in, const int* in_sizes, int n_in,
                              void* d_out, int out_size, void* d_ws, size_t ws_size,
                              hipStream_t stream)
{
  const float* inputs     = (const float*)d_in[0];
  const float* init_slots = (const float*)d_in[1];
  const float* ln_in_w    = (const float*)d_in[2];
  const float* ln_in_b    = (const float*)d_in[3];
  const float* ln_s_w     = (const float*)d_in[4];
  const float* ln_s_b     = (const float*)d_in[5];
  const float* ln_m_w     = (const float*)d_in[6];
  const float* ln_m_b     = (const float*)d_in[7];
  const float* wq         = (const float*)d_in[8];
  const float* wk         = (const float*)d_in[9];
  const float* wv         = (const float*)d_in[10];
  const float* w_ih       = (const float*)d_in[11];
  const float* w_hh       = (const float*)d_in[12];
  const float* b_ih       = (const float*)d_in[13];
  const float* b_hh       = (const float*)d_in[14];
  const float* mlp_w1     = (const float*)d_in[15];
  const float* mlp_b1     = (const float*)d_in[16];
  const float* mlp_w2     = (const float*)d_in[17];
  const float* mlp_b2     = (const float*)d_in[18];

  // workspace layout (floats); total ~16.1 MiB
  float* ws    = (float*)d_ws;
  float* wprepT= ws;                 // 8192
  float* mt    = ws + 8192;          // 64 (m[32], t[32])
  float* qbuf  = ws + 8320;          // 4096
  float* upd   = ws + 12416;         // 4096
  float* Abuf  = ws + 16512;         // 256
  float* kproj = ws + 16768;         // 2097152
  float* vproj = kproj + 2097152;    // 2097152

  float* out   = (float*)d_out;
  float* slots = out;                // [32,8,16]
  float* attn  = out + 4096;         // [32,8,4096]

  k_prep<<<32, 256, 0, stream>>>(ln_in_w, ln_in_b, wk, wv, init_slots,
                                 ln_s_w, ln_s_b, wq,
                                 wprepT, mt, qbuf, upd, Abuf, slots);
  k_proj<<<2048, 256, 0, stream>>>(inputs, wprepT, mt, kproj, vproj);
  for (int it = 0; it < 3; ++it) {
    int last = (it == 2);
    k_attn<<<512, 256, 0, stream>>>(kproj, vproj, qbuf, upd, Abuf, attn, last);
    k_gru<<<16, 256, 0, stream>>>(upd, Abuf, slots, qbuf,
                                  w_ih, w_hh, b_ih, b_hh,
                                  mlp_w1, mlp_b1, mlp_w2, mlp_b2,
                                  ln_m_w, ln_m_b, ln_s_w, ln_s_b,
                                  wq, last ? 0 : 1);
  }
  k_scale<<<256, 256, 0, stream>>>(attn, Abuf);
}

// Round 6
// 302.928 us; speedup vs baseline: 1.1161x; 1.1161x over previous
//
#include <hip/hip_runtime.h>
#include <cstddef>

// Problem constants: B=32, N=4096, D=256, K=8 slots, S=16, H=128, 3 iters.

typedef unsigned short ushort_t;
typedef __attribute__((ext_vector_type(8))) short short8;   // 8 bf16 = 4 VGPRs
typedef __attribute__((ext_vector_type(4))) float f32x4;

__device__ __forceinline__ float sigmoid_f(float x){ return 1.f/(1.f+__expf(-x)); }
__device__ __forceinline__ float tanh_f(float x){ return 1.f - 2.f/(__expf(2.f*x)+1.f); }

// fp32 -> bf16 (RNE), as raw bits
__device__ __forceinline__ ushort_t f2bf(float x){
  unsigned u = __float_as_uint(x);
  return (ushort_t)((u + 0x7FFFu + ((u>>16)&1u)) >> 16);
}
__device__ __forceinline__ float bf2f(ushort_t b){
  return __uint_as_float(((unsigned)b) << 16);
}

// ---------------- K0: prep (bf16-split weights, init slots, q1, zeros) -----
// Wh/Wl: [32 s][256 d] bf16 (s 0..15 -> k-proj, 16..31 -> v-proj), hi/lo split
// of lnw[d]*w[s][d].  mt[s] = sum_d quantized weight (so the LN-fold matches
// the MFMA dot exactly); mt[32+s] = sum_d lnb[d]*w[s][d].
__global__ __launch_bounds__(256) void k_prep(
    const float* __restrict__ lnw, const float* __restrict__ lnb,
    const float* __restrict__ wk, const float* __restrict__ wv,
    const float* __restrict__ init_slots,
    const float* __restrict__ ln_s_w, const float* __restrict__ ln_s_b,
    const float* __restrict__ wq,
    ushort_t* __restrict__ Wh, ushort_t* __restrict__ Wl,
    float* __restrict__ mt,
    float* __restrict__ qbuf, float* __restrict__ upd, float* __restrict__ Abuf,
    float* __restrict__ slots_out)
{
  int t = threadIdx.x;
  int i = blockIdx.x*256 + t;          // 32*256 == 8192 exactly
  {
    int s = i >> 8, d = i & 255;
    float w = (s < 16) ? wk[s*256+d] : wv[(s-16)*256+d];
    float w0 = lnw[d]*w;
    ushort_t hb = f2bf(w0);
    ushort_t lb = f2bf(w0 - bf2f(hb));
    Wh[i] = hb; Wl[i] = lb;
  }
  if (blockIdx.x != 0) return;
  // m[s] from QUANTIZED weights; t[s] exact fp32
  {
    int s = t >> 3, j = t & 7;
    float m = 0.f, tv = 0.f;
    for (int d = j; d < 256; d += 8) {
      float w = (s < 16) ? wk[s*256+d] : wv[(s-16)*256+d];
      float w0 = lnw[d]*w;
      ushort_t hb = f2bf(w0);
      float hf = bf2f(hb);
      float lf = bf2f(f2bf(w0 - hf));
      m  += hf + lf;
      tv  = fmaf(lnb[d], w, tv);
    }
    m += __shfl_xor(m,1);  m += __shfl_xor(m,2);  m += __shfl_xor(m,4);
    tv += __shfl_xor(tv,1); tv += __shfl_xor(tv,2); tv += __shfl_xor(tv,4);
    if (j == 0) { mt[s] = m; mt[32+s] = tv; }
  }
  // init slots into d_out, zero accumulators (ws is poisoned before each launch)
  #pragma unroll
  for (int j2 = 0; j2 < 16; ++j2) {
    slots_out[t*16+j2] = init_slots[t*16+j2];
    upd[t*16+j2] = 0.f;
  }
  Abuf[t] = 0.f;
  // q for iteration 1: thread t = (b,k) row
  float sl[16];
  #pragma unroll
  for (int j2 = 0; j2 < 16; ++j2) sl[j2] = init_slots[t*16+j2];
  float mu = 0.f;
  #pragma unroll
  for (int j2 = 0; j2 < 16; ++j2) mu += sl[j2];
  mu *= (1.f/16.f);
  float var = 0.f;
  #pragma unroll
  for (int j2 = 0; j2 < 16; ++j2) { float d = sl[j2]-mu; var = fmaf(d,d,var); }
  var *= (1.f/16.f);
  float rstd = rsqrtf(var + 1e-5f);
  float y[16];
  #pragma unroll
  for (int j2 = 0; j2 < 16; ++j2) y[j2] = (sl[j2]-mu)*rstd*ln_s_w[j2] + ln_s_b[j2];
  #pragma unroll
  for (int tq = 0; tq < 16; ++tq) {
    float q = 0.f;
    #pragma unroll
    for (int s2 = 0; s2 < 16; ++s2) q = fmaf(y[s2], wq[tq*16+s2], q);
    qbuf[t*16+tq] = q;
  }
}

// ---------------- K1: fused LayerNorm + K/V projection via MFMA ------------
// Block = 256 threads = 4 waves, 64 rows; wave w owns rows [w*16, w*16+16).
// mfma_f32_16x16x32_bf16, hi/lo split (3 passes, ll dropped -> ~1e-4 abs).
// A-frag A[m=lane&15][k=quad*8+j]: per lane 8 consecutive fp32 of row m ->
// plain row-major global loads, NO LDS, no scalar-weight SGPR thrash (the
// rounds 2-5 killer: 512 weight floats/chunk can't fit SGPRs, s_load reissue
// forced lgkmcnt(0) drains of all ds_reads).  B-frag B[n=lane&15][k=quad*8+j]
// from pre-split bf16 Wh/Wl: 16 B/lane vector loads, L1-resident.
// LN folded: out[n] = rstd*(dot - mu*m[n]) + t[n]; row stats in fp32 on the
// side, reduced across quads by 2 shuffles.  C/D: col=lane&15, row=quad*4+reg.
__global__ __launch_bounds__(256, 4) void k_proj(
    const float* __restrict__ x, const ushort_t* __restrict__ Wh,
    const ushort_t* __restrict__ Wl, const float* __restrict__ mt,
    float* __restrict__ kout, float* __restrict__ vout)
{
  int t = threadIdx.x;
  int w = t >> 6, lane = t & 63;
  int m = lane & 15, quad = lane >> 4;     // m doubles as C-col n
  int r0w = blockIdx.x*64 + w*16;
  const float* xr = x + (size_t)(r0w + m)*256 + quad*8;
  const ushort_t* wh0 = Wh + (size_t)m*256 + quad*8;   // n-tile 0 (k-proj)
  const ushort_t* wh1 = wh0 + 16*256;                  // n-tile 1 (v-proj)
  const ushort_t* wl0 = Wl + (size_t)m*256 + quad*8;
  const ushort_t* wl1 = wl0 + 16*256;

  f32x4 acck = {0.f,0.f,0.f,0.f}, accv = {0.f,0.f,0.f,0.f};
  float sum = 0.f, sumsq = 0.f;

  #pragma unroll
  for (int kk = 0; kk < 8; ++kk) {
    float4 a0 = *(const float4*)(xr + kk*32);
    float4 a1 = *(const float4*)(xr + kk*32 + 4);
    short8 bh_k = *(const short8*)(wh0 + kk*32);
    short8 bh_v = *(const short8*)(wh1 + kk*32);
    short8 bl_k = *(const short8*)(wl0 + kk*32);
    short8 bl_v = *(const short8*)(wl1 + kk*32);
    float xv[8] = {a0.x,a0.y,a0.z,a0.w, a1.x,a1.y,a1.z,a1.w};
    short8 ah, al;
    #pragma unroll
    for (int j = 0; j < 8; ++j) {
      float v = xv[j];
      sum += v; sumsq = fmaf(v, v, sumsq);
      ushort_t hb = f2bf(v);
      ushort_t lb = f2bf(v - bf2f(hb));
      ah[j] = (short)hb; al[j] = (short)lb;
    }
    acck = __builtin_amdgcn_mfma_f32_16x16x32_bf16(ah, bh_k, acck, 0, 0, 0);
    accv = __builtin_amdgcn_mfma_f32_16x16x32_bf16(ah, bh_v, accv, 0, 0, 0);
    acck = __builtin_amdgcn_mfma_f32_16x16x32_bf16(al, bh_k, acck, 0, 0, 0);
    accv = __builtin_amdgcn_mfma_f32_16x16x32_bf16(al, bh_v, accv, 0, 0, 0);
    acck = __builtin_amdgcn_mfma_f32_16x16x32_bf16(ah, bl_k, acck, 0, 0, 0);
    accv = __builtin_amdgcn_mfma_f32_16x16x32_bf16(ah, bl_v, accv, 0, 0, 0);
  }

  // full row-m stats (each quad covered 64 of 256 cols)
  sum   += __shfl_xor(sum, 16);  sum   += __shfl_xor(sum, 32);
  sumsq += __shfl_xor(sumsq, 16); sumsq += __shfl_xor(sumsq, 32);

  float mtk  = mt[m],    mtv  = mt[16+m];
  float mtkb = mt[32+m], mtvb = mt[48+m];
  #pragma unroll
  for (int r = 0; r < 4; ++r) {
    int row = quad*4 + r;                  // C row for this reg
    float s_ = __shfl(sum,   row);         // lane `row` holds row-`row` stats
    float q_ = __shfl(sumsq, row);
    float mu = s_*(1.f/256.f);
    float var = q_*(1.f/256.f) - mu*mu;
    float rstd = rsqrtf(var + 1e-5f);
    float ok = fmaf(rstd, acck[r] - mu*mtk, mtkb);
    float ov = fmaf(rstd, accv[r] - mu*mtv, mtvb);
    kout[(size_t)(r0w + row)*16 + m] = ok;
    vout[(size_t)(r0w + row)*16 + m] = ov;
  }
}

// ---------------- K2: logits + softmax-over-slots + update accumulation ----
// Block = (b, chunk of 256 n). Stage k tile [n][s] (stride 20) and v tile
// transposed [s][n] (stride 260) via coalesced loads. Phase 1: per-n softmax
// over 8 slots -> ptile (stride 260) + EPS, optional global attn write.
// Phase 2: threads = (kk,s,half), float4 over n, atomicAdd partials.
__global__ __launch_bounds__(256) void k_attn(
    const float* __restrict__ kproj, const float* __restrict__ vproj,
    const float* __restrict__ qbuf,
    float* __restrict__ upd, float* __restrict__ Abuf,
    float* __restrict__ attn_out, int write_attn)
{
  __shared__ float qs[128];
  __shared__ float ktile[256*20];
  __shared__ float vtile[16*260];
  __shared__ float ptile[8*260];
  int b = blockIdx.x >> 4;
  int n0 = (blockIdx.x & 15) * 256;
  int t = threadIdx.x;

  const float* kbase = kproj + ((size_t)(b*4096 + n0))*16;
  const float* vbase = vproj + ((size_t)(b*4096 + n0))*16;
  {
    int nn = t >> 2, s0 = (t & 3)*4;
    #pragma unroll
    for (int i = 0; i < 4; ++i) {
      int n = i*64 + nn;
      float4 kf = *(const float4*)(kbase + n*16 + s0);
      *(float4*)&ktile[n*20 + s0] = kf;
      float4 vf = *(const float4*)(vbase + n*16 + s0);
      vtile[(s0+0)*260 + n] = vf.x;
      vtile[(s0+1)*260 + n] = vf.y;
      vtile[(s0+2)*260 + n] = vf.z;
      vtile[(s0+3)*260 + n] = vf.w;
    }
  }
  if (t < 128) qs[t] = qbuf[b*128 + t];
  __syncthreads();

  {
    float4 kv[4];
    #pragma unroll
    for (int i = 0; i < 4; ++i) kv[i] = *(const float4*)&ktile[t*20 + i*4];
    const float4* q4 = (const float4*)qs;
    float lg[8];
    #pragma unroll
    for (int kk = 0; kk < 8; ++kk) {
      float4 a4 = make_float4(0.f,0.f,0.f,0.f);
      #pragma unroll
      for (int i = 0; i < 4; ++i) {
        float4 q = q4[kk*4+i];
        a4.x = fmaf(q.x, kv[i].x, a4.x);
        a4.y = fmaf(q.y, kv[i].y, a4.y);
        a4.z = fmaf(q.z, kv[i].z, a4.z);
        a4.w = fmaf(q.w, kv[i].w, a4.w);
      }
      lg[kk] = ((a4.x+a4.y)+(a4.z+a4.w))*0.25f;  // scale = 16^-0.5
    }
    float mx = lg[0];
    #pragma unroll
    for (int kk = 1; kk < 8; ++kk) mx = fmaxf(mx, lg[kk]);
    float se = 0.f;
    #pragma unroll
    for (int kk = 0; kk < 8; ++kk) { lg[kk] = __expf(lg[kk]-mx); se += lg[kk]; }
    float inv = 1.f/se;
    #pragma unroll
    for (int kk = 0; kk < 8; ++kk) {
      float pv = fmaf(lg[kk], inv, 1e-8f);   // softmax + EPS (pre-renorm)
      ptile[kk*260 + t] = pv;
      if (write_attn) attn_out[((size_t)(b*8+kk))*4096 + n0 + t] = pv;
    }
  }
  __syncthreads();
  {
    int kk = t >> 5, r = t & 31, s = r >> 1, half = r & 1;
    const float4* pr = (const float4*)(ptile + kk*260 + half*128);
    const float4* vr = (const float4*)(vtile + s*260 + half*128);
    float4 a4 = make_float4(0.f,0.f,0.f,0.f);
    float4 s4 = make_float4(0.f,0.f,0.f,0.f);
    #pragma unroll 8
    for (int i = 0; i < 32; ++i) {
      float4 pv = pr[i], vv = vr[i];
      s4.x += pv.x; s4.y += pv.y; s4.z += pv.z; s4.w += pv.w;
      a4.x = fmaf(pv.x, vv.x, a4.x);
      a4.y = fmaf(pv.y, vv.y, a4.y);
      a4.z = fmaf(pv.z, vv.z, a4.z);
      a4.w = fmaf(pv.w, vv.w, a4.w);
    }
    float acc  = (a4.x+a4.y)+(a4.z+a4.w);
    float asum = (s4.x+s4.y)+(s4.z+s4.w);
    acc  += __shfl_xor(acc, 1);
    asum += __shfl_xor(asum, 1);
    if (half == 0) {
      atomicAdd(upd + (b*8+kk)*16 + s, acc);
      if (s == 0) atomicAdd(Abuf + b*8 + kk, asum);
    }
  }
}

// ---------------- K3: GRU cell + LN + MLP + slots update + next-iter q -----
// 16 blocks x 256 threads; thread = (b,k,s); 16-lane group per (b,k).
__global__ __launch_bounds__(256) void k_gru(
    float* __restrict__ upd, float* __restrict__ Abuf,
    float* __restrict__ slots, float* __restrict__ qbuf,
    const float* __restrict__ w_ih, const float* __restrict__ w_hh,
    const float* __restrict__ b_ih, const float* __restrict__ b_hh,
    const float* __restrict__ mlp_w1, const float* __restrict__ mlp_b1,
    const float* __restrict__ mlp_w2, const float* __restrict__ mlp_b2,
    const float* __restrict__ ln_m_w, const float* __restrict__ ln_m_b,
    const float* __restrict__ ln_s_w, const float* __restrict__ ln_s_b,
    const float* __restrict__ wq, int prep_next)
{
  __shared__ float s_wih[48*17], s_whh[48*17];   // stride 17: conflict-free
  __shared__ float s_bih[48], s_bhh[48];
  __shared__ float s_w1[128*17], s_b1[128];
  __shared__ float s_w2[16*129], s_b2[16];       // stride 129: conflict-free
  __shared__ float s_lnmw[16], s_lnmb[16], s_lnsw[16], s_lnsb[16];
  __shared__ float s_wq[16*17];
  int t = threadIdx.x;
  for (int i = t; i < 768; i += 256) {
    int g = i >> 4, j = i & 15;
    s_wih[g*17+j] = w_ih[i];
    s_whh[g*17+j] = w_hh[i];
  }
  for (int i = t; i < 2048; i += 256) {
    int r = i >> 4, c = i & 15;
    s_w1[r*17+c] = mlp_w1[i];
    int r2 = i >> 7, c2 = i & 127;
    s_w2[r2*129+c2] = mlp_w2[i];
  }
  if (t < 48) { s_bih[t] = b_ih[t]; s_bhh[t] = b_hh[t]; }
  if (t < 128) s_b1[t] = mlp_b1[t];
  if (t < 16) {
    s_b2[t] = mlp_b2[t];
    s_lnmw[t] = ln_m_w[t]; s_lnmb[t] = ln_m_b[t];
    s_lnsw[t] = ln_s_w[t]; s_lnsb[t] = ln_s_b[t];
  }
  for (int i = t; i < 256; i += 256) {
    int r = i >> 4, c = i & 15;
    s_wq[r*17+c] = wq[i];
  }
  __syncthreads();

  int bk = blockIdx.x*16 + (t >> 4);
  int s = t & 15;
  int laneBase = (t & 63) & ~15;   // 16-lane group lives inside one wave

  float inv = 1.f / Abuf[bk];
  float u[16], h[16];
  #pragma unroll
  for (int j = 0; j < 16; ++j) {
    u[j] = upd[bk*16+j] * inv;     // normalized updates
    h[j] = slots[bk*16+j];         // slots_prev
  }
  float hs = slots[bk*16+s];       // avoid dynamic reg-array index

  float gir = s_bih[s],  giz = s_bih[16+s], gin = s_bih[32+s];
  float ghr = s_bhh[s],  ghz = s_bhh[16+s], ghn = s_bhh[32+s];
  #pragma unroll
  for (int j = 0; j < 16; ++j) {
    gir = fmaf(u[j], s_wih[s*17+j], gir);
    giz = fmaf(u[j], s_wih[(16+s)*17+j], giz);
    gin = fmaf(u[j], s_wih[(32+s)*17+j], gin);
    ghr = fmaf(h[j], s_whh[s*17+j], ghr);
    ghz = fmaf(h[j], s_whh[(16+s)*17+j], ghz);
    ghn = fmaf(h[j], s_whh[(32+s)*17+j], ghn);
  }
  float rr = sigmoid_f(gir + ghr);
  float zz = sigmoid_f(giz + ghz);
  float nn = tanh_f(gin + rr*ghn);
  float hn = (1.f-zz)*nn + zz*hs;

  // LayerNorm(h) over the 16-lane group
  float ssum = hn;
  #pragma unroll
  for (int m = 1; m < 16; m <<= 1) ssum += __shfl_xor(ssum, m);
  float mu = ssum*(1.f/16.f);
  float dv = hn - mu;
  float vs = dv*dv;
  #pragma unroll
  for (int m = 1; m < 16; m <<= 1) vs += __shfl_xor(vs, m);
  float rstd = rsqrtf(vs*(1.f/16.f) + 1e-5f);
  float y = dv*rstd*s_lnmw[s] + s_lnmb[s];

  float yv[16];
  #pragma unroll
  for (int j = 0; j < 16; ++j) yv[j] = __shfl(y, laneBase + j);

  // MLP layer 1: thread s owns hidden units j = i*16+s (bank-friendly)
  float h1[8];
  #pragma unroll
  for (int i = 0; i < 8; ++i) {
    int jj = i*16 + s;
    float a = s_b1[jj];
    #pragma unroll
    for (int q = 0; q < 16; ++q) a = fmaf(yv[q], s_w1[jj*17+q], a);
    h1[i] = fmaxf(a, 0.f);
  }
  // MLP layer 2 via shuffles
  float o = s_b2[s];
  #pragma unroll
  for (int i = 0; i < 8; ++i) {
    #pragma unroll
    for (int sp = 0; sp < 16; ++sp) {
      float hv = __shfl(h1[i], laneBase + sp);
      o = fmaf(hv, s_w2[s*129 + i*16 + sp], o);
    }
  }
  float slot_new = hn + o;
  slots[bk*16+s] = slot_new;

  if (prep_next) {
    // q for next iteration: wq @ LN_s(slots_new)
    float ss = slot_new;
    #pragma unroll
    for (int m = 1; m < 16; m <<= 1) ss += __shfl_xor(ss, m);
    float mu2 = ss*(1.f/16.f);
    float d2 = slot_new - mu2;
    float v2 = d2*d2;
    #pragma unroll
    for (int m = 1; m < 16; m <<= 1) v2 += __shfl_xor(v2, m);
    float rstd2 = rsqrtf(v2*(1.f/16.f) + 1e-5f);
    float y2 = d2*rstd2*s_lnsw[s] + s_lnsb[s];
    float qv = 0.f;
    #pragma unroll
    for (int sp = 0; sp < 16; ++sp) qv = fmaf(__shfl(y2, laneBase+sp), s_wq[s*17+sp], qv);
    qbuf[bk*16+s] = qv;
    // zero accumulators for next iteration (reads above are same-wave lockstep)
    upd[bk*16+s] = 0.f;
    if (s == 0) Abuf[bk] = 0.f;
  }
}

// ---------------- K4: normalize attn rows by A[b,k] ----------------
__global__ __launch_bounds__(256) void k_scale(float* __restrict__ attn,
                                               const float* __restrict__ Abuf)
{
  int bk = blockIdx.x;
  float inv = 1.f / Abuf[bk];
  float4* p = (float4*)(attn + (size_t)bk*4096);
  #pragma unroll 4
  for (int i = threadIdx.x; i < 1024; i += 256) {
    float4 v = p[i];
    v.x *= inv; v.y *= inv; v.z *= inv; v.w *= inv;
    p[i] = v;
  }
}

extern "C" void kernel_launch(void* const* d_in, const int* in_sizes, int n_in,
                              void* d_out, int out_size, void* d_ws, size_t ws_size,
                              hipStream_t stream)
{
  const float* inputs     = (const float*)d_in[0];
  const float* init_slots = (const float*)d_in[1];
  const float* ln_in_w    = (const float*)d_in[2];
  const float* ln_in_b    = (const float*)d_in[3];
  const float* ln_s_w     = (const float*)d_in[4];
  const float* ln_s_b     = (const float*)d_in[5];
  const float* ln_m_w     = (const float*)d_in[6];
  const float* ln_m_b     = (const float*)d_in[7];
  const float* wq         = (const float*)d_in[8];
  const float* wk         = (const float*)d_in[9];
  const float* wv         = (const float*)d_in[10];
  const float* w_ih       = (const float*)d_in[11];
  const float* w_hh       = (const float*)d_in[12];
  const float* b_ih       = (const float*)d_in[13];
  const float* b_hh       = (const float*)d_in[14];
  const float* mlp_w1     = (const float*)d_in[15];
  const float* mlp_b1     = (const float*)d_in[16];
  const float* mlp_w2     = (const float*)d_in[17];
  const float* mlp_b2     = (const float*)d_in[18];

  // workspace layout (floats); total ~16.1 MiB
  float* ws    = (float*)d_ws;
  ushort_t* Wh = (ushort_t*)ws;            // 8192 ushorts  (ws[0..4096))
  ushort_t* Wl = (ushort_t*)(ws + 4096);   // 8192 ushorts  (ws[4096..8192))
  float* mt    = ws + 8192;          // 64 (m[32], t[32])
  float* qbuf  = ws + 8320;          // 4096
  float* upd   = ws + 12416;         // 4096
  float* Abuf  = ws + 16512;         // 256
  float* kproj = ws + 16768;         // 2097152
  float* vproj = kproj + 2097152;    // 2097152

  float* out   = (float*)d_out;
  float* slots = out;                // [32,8,16]
  float* attn  = out + 4096;         // [32,8,4096]

  k_prep<<<32, 256, 0, stream>>>(ln_in_w, ln_in_b, wk, wv, init_slots,
                                 ln_s_w, ln_s_b, wq,
                                 Wh, Wl, mt, qbuf, upd, Abuf, slots);
  k_proj<<<2048, 256, 0, stream>>>(inputs, Wh, Wl, mt, kproj, vproj);
  for (int it = 0; it < 3; ++it) {
    int last = (it == 2);
    k_attn<<<512, 256, 0, stream>>>(kproj, vproj, qbuf, upd, Abuf, attn, last);
    k_gru<<<16, 256, 0, stream>>>(upd, Abuf, slots, qbuf,
                                  w_ih, w_hh, b_ih, b_hh,
                                  mlp_w1, mlp_b1, mlp_w2, mlp_b2,
                                  ln_m_w, ln_m_b, ln_s_w, ln_s_b,
                                  wq, last ? 0 : 1);
  }
  k_scale<<<256, 256, 0, stream>>>(attn, Abuf);
}